// Round 9
// baseline (1087.002 us; speedup 1.0000x reference)
//
#include <hip/hip_runtime.h>

// RETAIN forward. B=128 T=64 C=8000 H=256 D=16 G=768. All fp32 in/out;
// bf16 MFMA for matmuls, fp32 everywhere else.

typedef __attribute__((ext_vector_type(4))) float f32x4;
typedef __attribute__((ext_vector_type(8))) short short8;

__device__ inline short f2bf(float f) {
  unsigned u = __float_as_uint(f);
  u += 0x7fffu + ((u >> 16) & 1u);
  return (short)(u >> 16);
}
__device__ inline float sigf(float x) { return 1.f / (1.f + __expf(-x)); }
__device__ inline float tanh_fast(float x) {
  x = fminf(fmaxf(x, -15.f), 15.f);
  float e = __expf(2.f * x);
  return (e - 1.f) / (e + 1.f);
}

// ---------------- transpose embed_W [256,8000] -> Wt [8000,256] ----------------
__global__ void transpose_w(const float* __restrict__ in, float* __restrict__ outT) {
  __shared__ float tile[32][33];
  const int tx = threadIdx.x, ty = threadIdx.y;
  const int c0 = blockIdx.x * 32, h0 = blockIdx.y * 32;
#pragma unroll
  for (int k = 0; k < 4; ++k)
    tile[ty * 4 + k][tx] = in[(long)(h0 + ty * 4 + k) * 8000 + c0 + tx];
  __syncthreads();
#pragma unroll
  for (int k = 0; k < 4; ++k)
    outT[(long)(c0 + ty * 4 + k) * 256 + h0 + tx] = tile[tx][ty * 4 + k];
}

// ---------------- pad cls_W1/dl_W1 [256,272] -> [256,288] (zeros) ----------------
__global__ __launch_bounds__(256) void pad_w1(const float* __restrict__ w1,
                                              const float* __restrict__ w1d,
                                              float* __restrict__ o1,
                                              float* __restrict__ o2) {
  int idx = blockIdx.x * 256 + threadIdx.x;
  if (idx >= 2 * 256 * 288) return;
  int half = idx / (256 * 288);
  int r = idx % (256 * 288);
  int n = r / 288, k = r % 288;
  float v = (k < 272) ? (half ? w1d[n * 272 + k] : w1[n * 272 + k]) : 0.f;
  if (half) o2[r] = v; else o1[r] = v;
}

// ---------------- zero exchange flags ----------------
__global__ void zero_flags(int* __restrict__ flags) { flags[threadIdx.x] = 0; }

// ---------------- sparse embed: emb[bt,h] = b[h] + sum_c x!=0 * Wt[c,h] ----------------
__global__ __launch_bounds__(256) void embed_sparse(const float* __restrict__ x,
                                                    const float* __restrict__ Wt,
                                                    const float* __restrict__ eb,
                                                    float* __restrict__ emb) {
  __shared__ int sidx[512];
  __shared__ float sval[512];
  __shared__ int scnt;
  const int bt = blockIdx.x;  // 0..8191
  const int tid = threadIdx.x;
  if (tid == 0) scnt = 0;
  __syncthreads();
  const float* xr = x + (long)bt * 8000;
  for (int i = tid; i < 2000; i += 256) {
    float4 v = ((const float4*)xr)[i];
    if (v.x != 0.f) { int p = atomicAdd(&scnt, 1); if (p < 512) { sidx[p] = i * 4 + 0; sval[p] = v.x; } }
    if (v.y != 0.f) { int p = atomicAdd(&scnt, 1); if (p < 512) { sidx[p] = i * 4 + 1; sval[p] = v.y; } }
    if (v.z != 0.f) { int p = atomicAdd(&scnt, 1); if (p < 512) { sidx[p] = i * 4 + 2; sval[p] = v.z; } }
    if (v.w != 0.f) { int p = atomicAdd(&scnt, 1); if (p < 512) { sidx[p] = i * 4 + 3; sval[p] = v.w; } }
  }
  __syncthreads();
  const int n = min(scnt, 512);
  float acc = eb[tid];
  for (int i = 0; i < n; ++i) acc += sval[i] * Wt[(long)sidx[i] * 256 + tid];
  emb[(long)bt * 256 + tid] = acc;
}

// ---------------- generic GEMM: C[M,N] = act(A[M,K] @ B[N,K]^T + bias) ----------------
__global__ __launch_bounds__(256) void gemm_bt(const float* __restrict__ A,
                                               const float* __restrict__ B,
                                               const float* __restrict__ bias,
                                               float* __restrict__ C,
                                               int M, int N, int K, int ldc, int act) {
  __shared__ short As[64][40];
  __shared__ short Bs[64][40];
  const int tid = threadIdx.x;
  const int lane = tid & 63, wave = tid >> 6;
  const int wm = wave >> 1, wn = wave & 1;
  const int l15 = lane & 15, lhi = lane >> 4;
  const int m0 = blockIdx.y * 64, n0 = blockIdx.x * 64;
  const int srow = tid >> 2, scol = (tid & 3) * 8;
  f32x4 acc[2][2];
#pragma unroll
  for (int i = 0; i < 2; ++i)
#pragma unroll
    for (int j = 0; j < 2; ++j) acc[i][j] = (f32x4){0.f, 0.f, 0.f, 0.f};

  for (int k0 = 0; k0 < K; k0 += 32) {
    __syncthreads();
    {
      const float* p = A + (long)(m0 + srow) * K + k0 + scol;
      float4 f0 = *(const float4*)p;
      float4 f1 = *(const float4*)(p + 4);
      short8 v;
      v[0] = f2bf(f0.x); v[1] = f2bf(f0.y); v[2] = f2bf(f0.z); v[3] = f2bf(f0.w);
      v[4] = f2bf(f1.x); v[5] = f2bf(f1.y); v[6] = f2bf(f1.z); v[7] = f2bf(f1.w);
      *(short8*)&As[srow][scol] = v;
      const float* q = B + (long)(n0 + srow) * K + k0 + scol;
      float4 g0 = *(const float4*)q;
      float4 g1 = *(const float4*)(q + 4);
      short8 u;
      u[0] = f2bf(g0.x); u[1] = f2bf(g0.y); u[2] = f2bf(g0.z); u[3] = f2bf(g0.w);
      u[4] = f2bf(g1.x); u[5] = f2bf(g1.y); u[6] = f2bf(g1.z); u[7] = f2bf(g1.w);
      *(short8*)&Bs[srow][scol] = u;
    }
    __syncthreads();
    short8 af0 = *(const short8*)&As[wm * 32 + l15][lhi * 8];
    short8 af1 = *(const short8*)&As[wm * 32 + 16 + l15][lhi * 8];
    short8 bf0 = *(const short8*)&Bs[wn * 32 + l15][lhi * 8];
    short8 bf1 = *(const short8*)&Bs[wn * 32 + 16 + l15][lhi * 8];
    acc[0][0] = __builtin_amdgcn_mfma_f32_16x16x32_bf16(af0, bf0, acc[0][0], 0, 0, 0);
    acc[0][1] = __builtin_amdgcn_mfma_f32_16x16x32_bf16(af0, bf1, acc[0][1], 0, 0, 0);
    acc[1][0] = __builtin_amdgcn_mfma_f32_16x16x32_bf16(af1, bf0, acc[1][0], 0, 0, 0);
    acc[1][1] = __builtin_amdgcn_mfma_f32_16x16x32_bf16(af1, bf1, acc[1][1], 0, 0, 0);
  }
#pragma unroll
  for (int j = 0; j < 2; ++j) {
    const int col = n0 + wn * 32 + j * 16 + l15;
    const float bv = bias[col];
#pragma unroll
    for (int i = 0; i < 2; ++i) {
#pragma unroll
      for (int r = 0; r < 4; ++r) {
        const int row = m0 + wm * 32 + i * 16 + lhi * 4 + r;
        float v = acc[i][j][r] + bv;
        if (act == 1) v = fmaxf(v, 0.f);
        else if (act == 2) v = tanh_fast(v);
        C[(long)row * ldc + col] = v;
      }
    }
  }
}

// ---------------- GRU scan v9: column-split + device-scope h exchange ----------------
// 32 blocks x 512 thr: (gru 2) x (batch-group 2 of 64) x (col-split 8 of 32 cols).
// Weights in LDS (48 KB) -> ~0 register demand (ends the R1-R8 allocator fight).
// Per step: MFMA own 32 cols (all 3 gates, thread-local r/z/n), publish own
// h-slice as f32 device-scope atomic stores (parity double-buffer), flag (monotonic
// counter), spin-fetch 7 peer slices with device-scope atomic loads -> LDS.
// Raw s_barrier + counted waits; xp staged via global_load_lds, double-buffered.
__global__ __launch_bounds__(512, 2)
void gru_scan_x(const float* __restrict__ xpa,
                const float* __restrict__ xpb,
                const float* __restrict__ aWhh,
                const float* __restrict__ bWhh,
                const float* __restrict__ abhh,
                const float* __restrict__ bbhh,
                float* __restrict__ aout,
                float* __restrict__ bout,
                float* __restrict__ hx,
                int* __restrict__ flags) {
  const int tid = threadIdx.x;
  const int lane = tid & 63, w = tid >> 6;   // 8 waves
  const int l15 = lane & 15, lhi = lane >> 4;
  const int gru = blockIdx.x >> 4;
  const int grp = (blockIdx.x >> 3) & 1;
  const int split = blockIdx.x & 7;
  const int c0 = split * 32, B0 = grp * 64;
  const int rt = w & 3, chalf = w >> 2;
  const int cl = chalf * 16 + l15;           // own col-local 0..31
  const int col = c0 + cl;                   // global h col
  const float* xp  = gru ? xpb : xpa;
  const float* Whh = gru ? bWhh : aWhh;
  const float* bhh = gru ? bbhh : abhh;
  float* outp = gru ? bout : aout;
  float* hxg = hx + (long)((gru * 2 + grp) * 8) * 2 * 64 * 32;  // [8 slices][2 par][64][32]
  int* flg = flags + gru * 16 + grp * 8;

  __shared__ short wlds[6][8][64][8];  // 48 KB: [ct][kt][lane][8bf16]
  __shared__ short hl[64][264];        // 33.8 KB, padded stride
  __shared__ float xpl[2][64][96];     // 48 KB: [par][b][g*32+c]

  // weights: ct covers outcols o=ct*16+l15 with gate g=ct>>1, c_local=(ct&1)*16+l15
#pragma unroll
  for (int i = 0; i < 6; ++i) {
    const int s = w * 6 + i;
    const int ct = s >> 3, kt = s & 7;
    const int grow = (ct >> 1) * 256 + c0 + (ct & 1) * 16 + l15;
    const float* p = Whh + (long)grow * 256 + kt * 32 + lhi * 8;
    float4 f0 = *(const float4*)p;
    float4 f1 = *(const float4*)(p + 4);
    short8 v;
    v[0] = f2bf(f0.x); v[1] = f2bf(f0.y); v[2] = f2bf(f0.z); v[3] = f2bf(f0.w);
    v[4] = f2bf(f1.x); v[5] = f2bf(f1.y); v[6] = f2bf(f1.z); v[7] = f2bf(f1.w);
    *(short8*)&wlds[ct][kt][lane][0] = v;
  }
  float bh[3];
#pragma unroll
  for (int g = 0; g < 3; ++g) bh[g] = bhh[g * 256 + col];
  for (int i = tid; i < 64 * 264; i += 512) (&hl[0][0])[i] = 0;

  // xp staging: 96 gld calls of 64 dwords; call q covers flats [q*64, q*64+64)
  auto STAGE = [&](int par, int tt) {
#pragma unroll
    for (int i = 0; i < 12; ++i) {
      const int q = w * 12 + i;
      const int flat0 = q * 64;
      const int flat = flat0 + lane;
      const int b = flat / 96;
      const int r = flat - b * 96;
      const int g = r >> 5, c = r & 31;
      const float* src = xp + ((long)(B0 + b) * 64 + tt) * 768 + g * 256 + c0 + c;
      __builtin_amdgcn_global_load_lds((const __attribute__((address_space(1))) unsigned int*)src,
                                       (__attribute__((address_space(3))) unsigned int*)(&xpl[par][0][0] + flat0),
                                       4, 0, 0);
    }
  };
  STAGE(0, 0);
  __syncthreads();  // drains vmcnt+lgkm: weights, hl zeros, xpl[0] ready

  float hreg[4] = {0.f, 0.f, 0.f, 0.f};

  for (int t = 0; t < 64; ++t) {
    const int par = t & 1;
    // MFMA: acc[g] over K=256; wave tile = batches rt*16..+16, cols chalf*16..+16, 3 gates
    f32x4 acc[3];
#pragma unroll
    for (int g = 0; g < 3; ++g) acc[g] = (f32x4){0.f, 0.f, 0.f, 0.f};
#pragma unroll
    for (int kt = 0; kt < 8; ++kt) {
      short8 a = *(const short8*)&hl[rt * 16 + l15][kt * 32 + lhi * 8];
#pragma unroll
      for (int g = 0; g < 3; ++g) {
        const int ct = 2 * g + chalf;
        short8 bf = *(const short8*)&wlds[ct][kt][lane][0];
        acc[g] = __builtin_amdgcn_mfma_f32_16x16x32_bf16(a, bf, acc[g], 0, 0, 0);
      }
    }
    asm volatile("s_waitcnt lgkmcnt(0)" ::: "memory");
    __builtin_amdgcn_s_barrier();                       // hl reads done everywhere
    asm volatile("s_waitcnt vmcnt(0)" ::: "memory");    // xpl[par] landed
    // elementwise (thread-local r,z,n), write own h + out + publish
    const int par2 = (t + 1) & 1;
#pragma unroll
    for (int j = 0; j < 4; ++j) {
      const int bl = rt * 16 + lhi * 4 + j;
      const float xr = xpl[par][bl][cl];
      const float xz = xpl[par][bl][32 + cl];
      const float xn = xpl[par][bl][64 + cl];
      const float r = sigf(xr + acc[0][j] + bh[0]);
      const float z = sigf(xz + acc[1][j] + bh[1]);
      const float n = tanh_fast(xn + r * (acc[2][j] + bh[2]));
      const float hn = (1.f - z) * n + z * hreg[j];
      hreg[j] = hn;
      hl[bl][col] = f2bf(hn);
      outp[((long)(B0 + bl) * 64 + t) * 256 + col] = hn;
      if (t < 63)
        __hip_atomic_store(hxg + ((split * 2 + par2) * 64 + bl) * 32 + cl, hn,
                           __ATOMIC_RELAXED, __HIP_MEMORY_SCOPE_AGENT);
    }
    if (t < 63) {
      asm volatile("s_waitcnt vmcnt(0) lgkmcnt(0)" ::: "memory");  // publish + hl drained
      __builtin_amdgcn_s_barrier();                                // ... for all waves
      if (tid == 0)
        __hip_atomic_store(&flg[split], t + 1, __ATOMIC_RELEASE, __HIP_MEMORY_SCOPE_AGENT);
      STAGE(par2, t + 1);  // xp for t+1 flies during fetch phase (counted, not drained)
      if (w >= 1) {        // waves 1..7 fetch the 7 peer slices
        const int p = (w - 1) + ((w - 1) >= split ? 1 : 0);
        int it = 0;
        while (__hip_atomic_load(&flg[p], __ATOMIC_ACQUIRE, __HIP_MEMORY_SCOPE_AGENT) < t + 1 &&
               ++it < (1 << 25))
          __builtin_amdgcn_s_sleep(2);
        const float* srcb = hxg + (long)(p * 2 + par2) * 64 * 32;
#pragma unroll
        for (int i = 0; i < 32; ++i) {
          const int flat = i * 64 + lane;
          const int b = flat >> 5, c = flat & 31;
          const float v = __hip_atomic_load(srcb + flat, __ATOMIC_RELAXED, __HIP_MEMORY_SCOPE_AGENT);
          hl[b][p * 32 + c] = f2bf(v);
        }
      }
      asm volatile("s_waitcnt lgkmcnt(0)" ::: "memory");
      __builtin_amdgcn_s_barrier();  // remote h staged; t+1 gld still in flight
    }
  }
}

// ---------------- e_alpha + softmax over T ----------------
__global__ __launch_bounds__(256) void alpha_softmax(const float* __restrict__ aout,
                                                     const float* __restrict__ aW,
                                                     const float* __restrict__ ab,
                                                     float* __restrict__ alpha) {
  __shared__ float part[64][4];
  const int b = blockIdx.x, tid = threadIdx.x;
  const int t = tid >> 2, q = tid & 3;
  const float* p = aout + (long)(b * 64 + t) * 256 + q * 64;
  const float* wv = aW + q * 64;
  float s = 0.f;
  for (int i = 0; i < 64; ++i) s += p[i] * wv[i];
  part[t][q] = s;
  __syncthreads();
  if (tid < 64) {
    float e = part[tid][0] + part[tid][1] + part[tid][2] + part[tid][3] + ab[0];
    float m = e;
    for (int k = 32; k; k >>= 1) m = fmaxf(m, __shfl_xor(m, k));
    float ex = __expf(e - m);
    float sum = ex;
    for (int k = 32; k; k >>= 1) sum += __shfl_xor(sum, k);
    alpha[b * 64 + tid] = ex / sum;
  }
}

// ---------------- context + combined[B,288] (context|demo|zero-pad) ----------------
__global__ __launch_bounds__(256) void context_combined(const float* __restrict__ alpha,
                                                        const float* __restrict__ emb,
                                                        const float* __restrict__ beta,
                                                        const float* __restrict__ demo,
                                                        float* __restrict__ comb) {
  const int b = blockIdx.x, h = threadIdx.x;
  float acc = 0.f;
  for (int t = 0; t < 64; ++t) {
    const float a = alpha[b * 64 + t];
    const long ix = (long)(b * 64 + t) * 256 + h;
    acc += a * emb[ix] * beta[ix];
  }
  comb[b * 288 + h] = acc;
  if (h < 16) comb[b * 288 + 256 + h] = demo[b * 16 + h];
  else if (h < 32) comb[b * 288 + 256 + h] = 0.f;
}

// ---------------- death/LOS head final dot ----------------
__global__ __launch_bounds__(64) void dl_head(const float* __restrict__ h2,
                                              const float* __restrict__ w,
                                              const float* __restrict__ bias,
                                              float* __restrict__ out) {
  const int b = blockIdx.x, lane = threadIdx.x;
  float s = 0.f;
#pragma unroll
  for (int i = 0; i < 4; ++i) s += h2[b * 256 + lane * 4 + i] * w[lane * 4 + i];
  for (int k = 32; k; k >>= 1) s += __shfl_xor(s, k);
  if (lane == 0) out[(long)b * 8001 + 8000] = s + bias[0];
}

extern "C" void kernel_launch(void* const* d_in, const int* in_sizes, int n_in,
                              void* d_out, int out_size, void* d_ws, size_t ws_size,
                              hipStream_t stream) {
  (void)in_sizes; (void)n_in; (void)out_size; (void)ws_size;
  const float* x      = (const float*)d_in[0];
  const float* demo   = (const float*)d_in[1];
  const float* embW   = (const float*)d_in[2];
  const float* embB   = (const float*)d_in[3];
  const float* aWih   = (const float*)d_in[4];
  const float* aWhh   = (const float*)d_in[5];
  const float* abih   = (const float*)d_in[6];
  const float* abhh   = (const float*)d_in[7];
  const float* bWih   = (const float*)d_in[8];
  const float* bWhh   = (const float*)d_in[9];
  const float* bbih   = (const float*)d_in[10];
  const float* bbhh   = (const float*)d_in[11];
  const float* attnAW = (const float*)d_in[12];
  const float* attnAb = (const float*)d_in[13];
  const float* attnBW = (const float*)d_in[14];
  const float* attnBb = (const float*)d_in[15];
  const float* clsW1  = (const float*)d_in[16];
  const float* clsb1  = (const float*)d_in[17];
  const float* clsW2  = (const float*)d_in[18];
  const float* clsb2  = (const float*)d_in[19];
  const float* dlW1   = (const float*)d_in[20];
  const float* dlb1   = (const float*)d_in[21];
  const float* dlW2   = (const float*)d_in[22];
  const float* dlb2   = (const float*)d_in[23];
  float* out = (float*)d_out;
  float* ws = (float*)d_ws;

  float* Wt    = ws;               // 2,048,000
  float* emb   = Wt + 2048000;     // 2,097,152
  float* xpa   = emb + 2097152;    // 6,291,456
  float* xpb   = xpa + 6291456;    // 6,291,456
  float* aoutB = xpb + 6291456;    // 2,097,152
  float* boutB = aoutB + 2097152;  // 2,097,152
  float* betaB = boutB + 2097152;  // 2,097,152
  float* alpha = betaB + 2097152;  // 8,192
  float* comb  = alpha + 8192;     // 36,864
  float* h1    = comb + 36864;     // 32,768
  float* h2    = h1 + 32768;       // 32,768
  float* W1p   = h2 + 32768;       // 73,728
  float* W1pd  = W1p + 73728;      // 73,728
  float* hx    = W1pd + 73728;     // 2*2*8*2*64*32 = 262,144
  int*   flags = (int*)(hx + 262144);  // 32 ints

  transpose_w<<<dim3(250, 8), dim3(32, 8), 0, stream>>>(embW, Wt);
  pad_w1<<<dim3(576), dim3(256), 0, stream>>>(clsW1, dlW1, W1p, W1pd);
  zero_flags<<<dim3(1), dim3(32), 0, stream>>>(flags);
  embed_sparse<<<dim3(8192), dim3(256), 0, stream>>>(x, Wt, embB, emb);
  gemm_bt<<<dim3(12, 128), dim3(256), 0, stream>>>(emb, aWih, abih, xpa, 8192, 768, 256, 768, 0);
  gemm_bt<<<dim3(12, 128), dim3(256), 0, stream>>>(emb, bWih, bbih, xpb, 8192, 768, 256, 768, 0);
  gru_scan_x<<<dim3(32), dim3(512), 0, stream>>>(xpa, xpb, aWhh, bWhh, abhh, bbhh,
                                                 aoutB, boutB, hx, flags);
  alpha_softmax<<<dim3(128), dim3(256), 0, stream>>>(aoutB, attnAW, attnAb, alpha);
  gemm_bt<<<dim3(4, 128), dim3(256), 0, stream>>>(boutB, attnBW, attnBb, betaB, 8192, 256, 256, 256, 2);
  context_combined<<<dim3(128), dim3(256), 0, stream>>>(alpha, emb, betaB, demo, comb);
  gemm_bt<<<dim3(4, 2), dim3(256), 0, stream>>>(comb, W1p, clsb1, h1, 128, 256, 288, 256, 1);
  gemm_bt<<<dim3(4, 2), dim3(256), 0, stream>>>(comb, W1pd, dlb1, h2, 128, 256, 288, 256, 1);
  gemm_bt<<<dim3(125, 2), dim3(256), 0, stream>>>(h1, clsW2, clsb2, out, 128, 8000, 256, 8001, 0);
  dl_head<<<dim3(128), dim3(64), 0, stream>>>(h2, dlW2, dlb2, out);
}

// Round 10
// 369.371 us; speedup vs baseline: 2.9428x; 2.9428x over previous
//
#include <hip/hip_runtime.h>

// RETAIN forward. B=128 T=64 C=8000 H=256 D=16 G=768. All fp32 in/out;
// bf16 MFMA for matmuls, fp32 everywhere else.

typedef __attribute__((ext_vector_type(4))) float f32x4;
typedef __attribute__((ext_vector_type(8))) short short8;

__device__ inline short f2bf(float f) {
  unsigned u = __float_as_uint(f);
  u += 0x7fffu + ((u >> 16) & 1u);
  return (short)(u >> 16);
}
__device__ inline float sigf(float x) { return 1.f / (1.f + __expf(-x)); }
__device__ inline float tanh_fast(float x) {
  x = fminf(fmaxf(x, -15.f), 15.f);
  float e = __expf(2.f * x);
  return (e - 1.f) / (e + 1.f);
}

// ---------------- transpose embed_W [256,8000] -> Wt [8000,256] ----------------
__global__ void transpose_w(const float* __restrict__ in, float* __restrict__ outT) {
  __shared__ float tile[32][33];
  const int tx = threadIdx.x, ty = threadIdx.y;
  const int c0 = blockIdx.x * 32, h0 = blockIdx.y * 32;
#pragma unroll
  for (int k = 0; k < 4; ++k)
    tile[ty * 4 + k][tx] = in[(long)(h0 + ty * 4 + k) * 8000 + c0 + tx];
  __syncthreads();
#pragma unroll
  for (int k = 0; k < 4; ++k)
    outT[(long)(c0 + ty * 4 + k) * 256 + h0 + tx] = tile[tx][ty * 4 + k];
}

// ---------------- pad cls_W1/dl_W1 [256,272] -> [256,288] (zeros) ----------------
__global__ __launch_bounds__(256) void pad_w1(const float* __restrict__ w1,
                                              const float* __restrict__ w1d,
                                              float* __restrict__ o1,
                                              float* __restrict__ o2) {
  int idx = blockIdx.x * 256 + threadIdx.x;
  if (idx >= 2 * 256 * 288) return;
  int half = idx / (256 * 288);
  int r = idx % (256 * 288);
  int n = r / 288, k = r % 288;
  float v = (k < 272) ? (half ? w1d[n * 272 + k] : w1[n * 272 + k]) : 0.f;
  if (half) o2[r] = v; else o1[r] = v;
}

// ---------------- pack W_hh into bf16 MFMA fragments ----------------
// frag F = (((gru*8 + kt)*3 + e)*16 + w)*64 + lane ; 8 shorts each.
// lane holds W[g = e*256 + w*16 + (lane&15)][kt*32 + (lane>>4)*8 + j]
__global__ __launch_bounds__(512) void pack_whh(const float* __restrict__ aWhh,
                                                const float* __restrict__ bWhh,
                                                short* __restrict__ wbf) {
  const int F = blockIdx.x * 512 + threadIdx.x;  // 0..49151
  int f = F;
  const int lane = f & 63; f >>= 6;
  const int w = f & 15; f >>= 4;
  const int e = f % 3; f /= 3;
  const int kt = f & 7; f >>= 3;
  const int gru = f;
  const float* W = gru ? bWhh : aWhh;
  const int g = e * 256 + w * 16 + (lane & 15);
  const int k = kt * 32 + (lane >> 4) * 8;
  const float* p = W + (long)g * 256 + k;
  short8 v;
#pragma unroll
  for (int j = 0; j < 8; ++j) v[j] = f2bf(p[j]);
  *(short8*)(wbf + (long)F * 8) = v;
}

// ---------------- sparse embed: emb[bt,h] = b[h] + sum_c x!=0 * Wt[c,h] ----------------
__global__ __launch_bounds__(256) void embed_sparse(const float* __restrict__ x,
                                                    const float* __restrict__ Wt,
                                                    const float* __restrict__ eb,
                                                    float* __restrict__ emb) {
  __shared__ int sidx[512];
  __shared__ float sval[512];
  __shared__ int scnt;
  const int bt = blockIdx.x;  // 0..8191
  const int tid = threadIdx.x;
  if (tid == 0) scnt = 0;
  __syncthreads();
  const float* xr = x + (long)bt * 8000;
  for (int i = tid; i < 2000; i += 256) {
    float4 v = ((const float4*)xr)[i];
    if (v.x != 0.f) { int p = atomicAdd(&scnt, 1); if (p < 512) { sidx[p] = i * 4 + 0; sval[p] = v.x; } }
    if (v.y != 0.f) { int p = atomicAdd(&scnt, 1); if (p < 512) { sidx[p] = i * 4 + 1; sval[p] = v.y; } }
    if (v.z != 0.f) { int p = atomicAdd(&scnt, 1); if (p < 512) { sidx[p] = i * 4 + 2; sval[p] = v.z; } }
    if (v.w != 0.f) { int p = atomicAdd(&scnt, 1); if (p < 512) { sidx[p] = i * 4 + 3; sval[p] = v.w; } }
  }
  __syncthreads();
  const int n = min(scnt, 512);
  float acc = eb[tid];
  for (int i = 0; i < n; ++i) acc += sval[i] * Wt[(long)sidx[i] * 256 + tid];
  emb[(long)bt * 256 + tid] = acc;
}

// ---------------- generic GEMM: C[M,N] = act(A[M,K] @ B[N,K]^T + bias) ----------------
__global__ __launch_bounds__(256) void gemm_bt(const float* __restrict__ A,
                                               const float* __restrict__ B,
                                               const float* __restrict__ bias,
                                               float* __restrict__ C,
                                               int M, int N, int K, int ldc, int act) {
  __shared__ short As[64][40];
  __shared__ short Bs[64][40];
  const int tid = threadIdx.x;
  const int lane = tid & 63, wave = tid >> 6;
  const int wm = wave >> 1, wn = wave & 1;
  const int l15 = lane & 15, lhi = lane >> 4;
  const int m0 = blockIdx.y * 64, n0 = blockIdx.x * 64;
  const int srow = tid >> 2, scol = (tid & 3) * 8;
  f32x4 acc[2][2];
#pragma unroll
  for (int i = 0; i < 2; ++i)
#pragma unroll
    for (int j = 0; j < 2; ++j) acc[i][j] = (f32x4){0.f, 0.f, 0.f, 0.f};

  for (int k0 = 0; k0 < K; k0 += 32) {
    __syncthreads();
    {
      const float* p = A + (long)(m0 + srow) * K + k0 + scol;
      float4 f0 = *(const float4*)p;
      float4 f1 = *(const float4*)(p + 4);
      short8 v;
      v[0] = f2bf(f0.x); v[1] = f2bf(f0.y); v[2] = f2bf(f0.z); v[3] = f2bf(f0.w);
      v[4] = f2bf(f1.x); v[5] = f2bf(f1.y); v[6] = f2bf(f1.z); v[7] = f2bf(f1.w);
      *(short8*)&As[srow][scol] = v;
      const float* q = B + (long)(n0 + srow) * K + k0 + scol;
      float4 g0 = *(const float4*)q;
      float4 g1 = *(const float4*)(q + 4);
      short8 u;
      u[0] = f2bf(g0.x); u[1] = f2bf(g0.y); u[2] = f2bf(g0.z); u[3] = f2bf(g0.w);
      u[4] = f2bf(g1.x); u[5] = f2bf(g1.y); u[6] = f2bf(g1.z); u[7] = f2bf(g1.w);
      *(short8*)&Bs[srow][scol] = u;
    }
    __syncthreads();
    short8 af0 = *(const short8*)&As[wm * 32 + l15][lhi * 8];
    short8 af1 = *(const short8*)&As[wm * 32 + 16 + l15][lhi * 8];
    short8 bf0 = *(const short8*)&Bs[wn * 32 + l15][lhi * 8];
    short8 bf1 = *(const short8*)&Bs[wn * 32 + 16 + l15][lhi * 8];
    acc[0][0] = __builtin_amdgcn_mfma_f32_16x16x32_bf16(af0, bf0, acc[0][0], 0, 0, 0);
    acc[0][1] = __builtin_amdgcn_mfma_f32_16x16x32_bf16(af0, bf1, acc[0][1], 0, 0, 0);
    acc[1][0] = __builtin_amdgcn_mfma_f32_16x16x32_bf16(af1, bf0, acc[1][0], 0, 0, 0);
    acc[1][1] = __builtin_amdgcn_mfma_f32_16x16x32_bf16(af1, bf1, acc[1][1], 0, 0, 0);
  }
#pragma unroll
  for (int j = 0; j < 2; ++j) {
    const int col = n0 + wn * 32 + j * 16 + l15;
    const float bv = bias[col];
#pragma unroll
    for (int i = 0; i < 2; ++i) {
#pragma unroll
      for (int r = 0; r < 4; ++r) {
        const int row = m0 + wm * 32 + i * 16 + lhi * 4 + r;
        float v = acc[i][j][r] + bv;
        if (act == 1) v = fmaxf(v, 0.f);
        else if (act == 2) v = tanh_fast(v);
        C[(long)row * ldc + col] = v;
      }
    }
  }
}

// ---------------- dual-B GEMM: xpa/xpb from emb in one pass (A read once) ----------------
__global__ __launch_bounds__(256) void gemm_dual(const float* __restrict__ A,
                                                 const float* __restrict__ B1,
                                                 const float* __restrict__ B2,
                                                 const float* __restrict__ bias1,
                                                 const float* __restrict__ bias2,
                                                 float* __restrict__ C1,
                                                 float* __restrict__ C2,
                                                 int K) {
  __shared__ short As[64][40];
  __shared__ short Bs1[64][40];
  __shared__ short Bs2[64][40];
  const int tid = threadIdx.x;
  const int lane = tid & 63, wave = tid >> 6;
  const int wm = wave >> 1, wn = wave & 1;
  const int l15 = lane & 15, lhi = lane >> 4;
  const int m0 = blockIdx.y * 64, n0 = blockIdx.x * 64;
  const int srow = tid >> 2, scol = (tid & 3) * 8;
  f32x4 acc1[2][2], acc2[2][2];
#pragma unroll
  for (int i = 0; i < 2; ++i)
#pragma unroll
    for (int j = 0; j < 2; ++j) {
      acc1[i][j] = (f32x4){0.f, 0.f, 0.f, 0.f};
      acc2[i][j] = (f32x4){0.f, 0.f, 0.f, 0.f};
    }

  for (int k0 = 0; k0 < K; k0 += 32) {
    __syncthreads();
    {
      const float* p = A + (long)(m0 + srow) * K + k0 + scol;
      float4 f0 = *(const float4*)p;
      float4 f1 = *(const float4*)(p + 4);
      short8 v;
      v[0] = f2bf(f0.x); v[1] = f2bf(f0.y); v[2] = f2bf(f0.z); v[3] = f2bf(f0.w);
      v[4] = f2bf(f1.x); v[5] = f2bf(f1.y); v[6] = f2bf(f1.z); v[7] = f2bf(f1.w);
      *(short8*)&As[srow][scol] = v;
      const float* q1 = B1 + (long)(n0 + srow) * K + k0 + scol;
      float4 g0 = *(const float4*)q1;
      float4 g1 = *(const float4*)(q1 + 4);
      short8 u;
      u[0] = f2bf(g0.x); u[1] = f2bf(g0.y); u[2] = f2bf(g0.z); u[3] = f2bf(g0.w);
      u[4] = f2bf(g1.x); u[5] = f2bf(g1.y); u[6] = f2bf(g1.z); u[7] = f2bf(g1.w);
      *(short8*)&Bs1[srow][scol] = u;
      const float* q2 = B2 + (long)(n0 + srow) * K + k0 + scol;
      float4 h0 = *(const float4*)q2;
      float4 h1 = *(const float4*)(q2 + 4);
      short8 t;
      t[0] = f2bf(h0.x); t[1] = f2bf(h0.y); t[2] = f2bf(h0.z); t[3] = f2bf(h0.w);
      t[4] = f2bf(h1.x); t[5] = f2bf(h1.y); t[6] = f2bf(h1.z); t[7] = f2bf(h1.w);
      *(short8*)&Bs2[srow][scol] = t;
    }
    __syncthreads();
    short8 af0 = *(const short8*)&As[wm * 32 + l15][lhi * 8];
    short8 af1 = *(const short8*)&As[wm * 32 + 16 + l15][lhi * 8];
    short8 b10 = *(const short8*)&Bs1[wn * 32 + l15][lhi * 8];
    short8 b11 = *(const short8*)&Bs1[wn * 32 + 16 + l15][lhi * 8];
    short8 b20 = *(const short8*)&Bs2[wn * 32 + l15][lhi * 8];
    short8 b21 = *(const short8*)&Bs2[wn * 32 + 16 + l15][lhi * 8];
    acc1[0][0] = __builtin_amdgcn_mfma_f32_16x16x32_bf16(af0, b10, acc1[0][0], 0, 0, 0);
    acc1[0][1] = __builtin_amdgcn_mfma_f32_16x16x32_bf16(af0, b11, acc1[0][1], 0, 0, 0);
    acc1[1][0] = __builtin_amdgcn_mfma_f32_16x16x32_bf16(af1, b10, acc1[1][0], 0, 0, 0);
    acc1[1][1] = __builtin_amdgcn_mfma_f32_16x16x32_bf16(af1, b11, acc1[1][1], 0, 0, 0);
    acc2[0][0] = __builtin_amdgcn_mfma_f32_16x16x32_bf16(af0, b20, acc2[0][0], 0, 0, 0);
    acc2[0][1] = __builtin_amdgcn_mfma_f32_16x16x32_bf16(af0, b21, acc2[0][1], 0, 0, 0);
    acc2[1][0] = __builtin_amdgcn_mfma_f32_16x16x32_bf16(af1, b20, acc2[1][0], 0, 0, 0);
    acc2[1][1] = __builtin_amdgcn_mfma_f32_16x16x32_bf16(af1, b21, acc2[1][1], 0, 0, 0);
  }
#pragma unroll
  for (int j = 0; j < 2; ++j) {
    const int col = n0 + wn * 32 + j * 16 + l15;
    const float bv1 = bias1[col];
    const float bv2 = bias2[col];
#pragma unroll
    for (int i = 0; i < 2; ++i) {
#pragma unroll
      for (int r = 0; r < 4; ++r) {
        const int row = m0 + wm * 32 + i * 16 + lhi * 4 + r;
        C1[(long)row * 768 + col] = acc1[i][j][r] + bv1;
        C2[(long)row * 768 + col] = acc2[i][j][r] + bv2;
      }
    }
  }
}

// ---------------- GRU scan v10: budgeted for the 64/64 arch/AGPR split ----------------
// 64 blocks x 1024 thr (16 waves). Wave w owns cols [w*16,w*16+16) x 3 gates.
// Weights (pre-packed bf16 frags): kt 0..3 in regs (48 <= 64 AGPR half),
// kt 4..5 in LDS (96 KB), kt 6..7 streamed from L2 each step (24 transient regs;
// arch half = 12 acc + 24 stream + ~20 misc <= 64). Zero spill by construction.
// xpl double-buffered; barrier2 is raw lgkmcnt(0)+s_barrier (no store drain).
__global__ __launch_bounds__(1024, 4)
void gru_scan(const float* __restrict__ xpa,
              const float* __restrict__ xpb,
              const short* __restrict__ wbf,
              const float* __restrict__ abhh,
              const float* __restrict__ bbhh,
              float* __restrict__ aout,
              float* __restrict__ bout) {
  const int tid = threadIdx.x;
  const int lane = tid & 63, w = tid >> 6;   // wave 0..15
  const int l15 = lane & 15, lhi = lane >> 4;
  const int gru = blockIdx.x >> 5, chunk = blockIdx.x & 31;
  const int b0 = chunk * 4;
  const float* xp  = gru ? xpb : xpa;
  const float* bhh = gru ? bbhh : abhh;
  float* outp = gru ? bout : aout;

  __shared__ short hl[16][264];            // 8.25 KB (rows 4..15 stay zero)
  __shared__ float xpl[2][4][772];         // 24.7 KB double-buffered xp slice
  __shared__ short wlds[2][16][3][64][8];  // 96 KB: kt 4,5 fragments

  // fragment pointer: F = (((gru*8+kt)*3+e)*16 + w)*64 + lane
  auto FR = [&](int kt, int e) -> const short8* {
    return (const short8*)(wbf + ((((long)gru * 8 + kt) * 3 + e) * 16 + w) * 512 + (long)lane * 8);
  };

  // kt 0..3 -> registers (target: AGPR half)
  short8 wf[3][4];
#pragma unroll
  for (int e = 0; e < 3; ++e)
#pragma unroll
    for (int kt = 0; kt < 4; ++kt) wf[e][kt] = *FR(kt, e);
  // kt 4..5 -> LDS
#pragma unroll
  for (int e = 0; e < 3; ++e)
#pragma unroll
    for (int kt = 4; kt < 6; ++kt) *(short8*)&wlds[kt - 4][w][e][lane][0] = *FR(kt, e);

  float bh[3];
#pragma unroll
  for (int e = 0; e < 3; ++e) bh[e] = bhh[e * 256 + w * 16 + l15];

  for (int i = tid; i < 16 * 264; i += 1024) (&hl[0][0])[i] = 0;

  // stage xp[t] into xpl[par]: waves 0..11, row=w/3, seg=w%3 (1KB contiguous)
  auto STAGE = [&](int par, int tt) {
    const int row = w / 3, seg = w % 3;
    const float* gp = xp + ((long)(b0 + row) * 64 + tt) * 768 + seg * 256 + lane * 4;
    __builtin_amdgcn_global_load_lds((const __attribute__((address_space(1))) unsigned int*)gp,
                                     (__attribute__((address_space(3))) unsigned int*)&xpl[par][row][seg * 256],
                                     16, 0, 0);
  };
  if (w < 12) STAGE(0, 0);
  __syncthreads();  // weights/hl visible, xpl[0] landed

  float hreg[4] = {0.f, 0.f, 0.f, 0.f};  // h state (lhi==0): col=w*16+l15, batch=j
  const int col = w * 16 + l15;

  for (int t = 0; t < 64; ++t) {
    const int par = t & 1;
    // streamed weights kt 6,7 (issued before MFMA block; latency hidden under it)
    short8 s60 = *FR(6, 0), s61 = *FR(6, 1), s62 = *FR(6, 2);
    short8 s70 = *FR(7, 0), s71 = *FR(7, 1), s72 = *FR(7, 2);

    f32x4 acc[3];
#pragma unroll
    for (int e = 0; e < 3; ++e) acc[e] = (f32x4){0.f, 0.f, 0.f, 0.f};
#pragma unroll
    for (int kt = 0; kt < 4; ++kt) {
      short8 a = *(const short8*)&hl[l15][kt * 32 + lhi * 8];
      acc[0] = __builtin_amdgcn_mfma_f32_16x16x32_bf16(a, wf[0][kt], acc[0], 0, 0, 0);
      acc[1] = __builtin_amdgcn_mfma_f32_16x16x32_bf16(a, wf[1][kt], acc[1], 0, 0, 0);
      acc[2] = __builtin_amdgcn_mfma_f32_16x16x32_bf16(a, wf[2][kt], acc[2], 0, 0, 0);
    }
#pragma unroll
    for (int kt = 4; kt < 6; ++kt) {
      short8 a = *(const short8*)&hl[l15][kt * 32 + lhi * 8];
#pragma unroll
      for (int e = 0; e < 3; ++e) {
        short8 wl = *(const short8*)&wlds[kt - 4][w][e][lane][0];
        acc[e] = __builtin_amdgcn_mfma_f32_16x16x32_bf16(a, wl, acc[e], 0, 0, 0);
      }
    }
    {
      short8 a = *(const short8*)&hl[l15][6 * 32 + lhi * 8];
      acc[0] = __builtin_amdgcn_mfma_f32_16x16x32_bf16(a, s60, acc[0], 0, 0, 0);
      acc[1] = __builtin_amdgcn_mfma_f32_16x16x32_bf16(a, s61, acc[1], 0, 0, 0);
      acc[2] = __builtin_amdgcn_mfma_f32_16x16x32_bf16(a, s62, acc[2], 0, 0, 0);
    }
    {
      short8 a = *(const short8*)&hl[l15][7 * 32 + lhi * 8];
      acc[0] = __builtin_amdgcn_mfma_f32_16x16x32_bf16(a, s70, acc[0], 0, 0, 0);
      acc[1] = __builtin_amdgcn_mfma_f32_16x16x32_bf16(a, s71, acc[1], 0, 0, 0);
      acc[2] = __builtin_amdgcn_mfma_f32_16x16x32_bf16(a, s72, acc[2], 0, 0, 0);
    }
    __syncthreads();  // barrier1: all hl reads done; xpl[par] landed (vmcnt drain)

    // elementwise GRU update (lhi==0 lanes own batches 0..3)
    if (lhi == 0) {
#pragma unroll
      for (int j = 0; j < 4; ++j) {
        const float r = sigf(xpl[par][j][col] + acc[0][j] + bh[0]);
        const float z = sigf(xpl[par][j][256 + col] + acc[1][j] + bh[1]);
        const float n = tanh_fast(xpl[par][j][512 + col] + r * (acc[2][j] + bh[2]));
        const float hn = (1.f - z) * n + z * hreg[j];
        hreg[j] = hn;
        hl[j][col] = f2bf(hn);
        outp[((long)(b0 + j) * 64 + t) * 256 + col] = hn;
      }
    }
    // barrier2: hl writes visible; no vmem drain needed (outp never read back)
    asm volatile("s_waitcnt lgkmcnt(0)" ::: "memory");
    __builtin_amdgcn_s_barrier();
    __builtin_amdgcn_sched_barrier(0);
    if (t + 1 < 64 && w < 12) STAGE(par ^ 1, t + 1);  // lands during t+1 MFMA phase
  }
}

// ---------------- e_alpha + softmax over T ----------------
__global__ __launch_bounds__(256) void alpha_softmax(const float* __restrict__ aout,
                                                     const float* __restrict__ aW,
                                                     const float* __restrict__ ab,
                                                     float* __restrict__ alpha) {
  __shared__ float part[64][4];
  const int b = blockIdx.x, tid = threadIdx.x;
  const int t = tid >> 2, q = tid & 3;
  const float* p = aout + (long)(b * 64 + t) * 256 + q * 64;
  const float* wv = aW + q * 64;
  float s = 0.f;
  for (int i = 0; i < 64; ++i) s += p[i] * wv[i];
  part[t][q] = s;
  __syncthreads();
  if (tid < 64) {
    float e = part[tid][0] + part[tid][1] + part[tid][2] + part[tid][3] + ab[0];
    float m = e;
    for (int k = 32; k; k >>= 1) m = fmaxf(m, __shfl_xor(m, k));
    float ex = __expf(e - m);
    float sum = ex;
    for (int k = 32; k; k >>= 1) sum += __shfl_xor(sum, k);
    alpha[b * 64 + tid] = ex / sum;
  }
}

// ---------------- context + combined[B,288] (context|demo|zero-pad) ----------------
__global__ __launch_bounds__(256) void context_combined(const float* __restrict__ alpha,
                                                        const float* __restrict__ emb,
                                                        const float* __restrict__ beta,
                                                        const float* __restrict__ demo,
                                                        float* __restrict__ comb) {
  const int b = blockIdx.x, h = threadIdx.x;
  float acc = 0.f;
  for (int t = 0; t < 64; ++t) {
    const float a = alpha[b * 64 + t];
    const long ix = (long)(b * 64 + t) * 256 + h;
    acc += a * emb[ix] * beta[ix];
  }
  comb[b * 288 + h] = acc;
  if (h < 16) comb[b * 288 + 256 + h] = demo[b * 16 + h];
  else if (h < 32) comb[b * 288 + 256 + h] = 0.f;
}

// ---------------- death/LOS head final dot ----------------
__global__ __launch_bounds__(64) void dl_head(const float* __restrict__ h2,
                                              const float* __restrict__ w,
                                              const float* __restrict__ bias,
                                              float* __restrict__ out) {
  const int b = blockIdx.x, lane = threadIdx.x;
  float s = 0.f;
#pragma unroll
  for (int i = 0; i < 4; ++i) s += h2[b * 256 + lane * 4 + i] * w[lane * 4 + i];
  for (int k = 32; k; k >>= 1) s += __shfl_xor(s, k);
  if (lane == 0) out[(long)b * 8001 + 8000] = s + bias[0];
}

extern "C" void kernel_launch(void* const* d_in, const int* in_sizes, int n_in,
                              void* d_out, int out_size, void* d_ws, size_t ws_size,
                              hipStream_t stream) {
  (void)in_sizes; (void)n_in; (void)out_size; (void)ws_size;
  const float* x      = (const float*)d_in[0];
  const float* demo   = (const float*)d_in[1];
  const float* embW   = (const float*)d_in[2];
  const float* embB   = (const float*)d_in[3];
  const float* aWih   = (const float*)d_in[4];
  const float* aWhh   = (const float*)d_in[5];
  const float* abih   = (const float*)d_in[6];
  const float* abhh   = (const float*)d_in[7];
  const float* bWih   = (const float*)d_in[8];
  const float* bWhh   = (const float*)d_in[9];
  const float* bbih   = (const float*)d_in[10];
  const float* bbhh   = (const float*)d_in[11];
  const float* attnAW = (const float*)d_in[12];
  const float* attnAb = (const float*)d_in[13];
  const float* attnBW = (const float*)d_in[14];
  const float* attnBb = (const float*)d_in[15];
  const float* clsW1  = (const float*)d_in[16];
  const float* clsb1  = (const float*)d_in[17];
  const float* clsW2  = (const float*)d_in[18];
  const float* clsb2  = (const float*)d_in[19];
  const float* dlW1   = (const float*)d_in[20];
  const float* dlb1   = (const float*)d_in[21];
  const float* dlW2   = (const float*)d_in[22];
  const float* dlb2   = (const float*)d_in[23];
  float* out = (float*)d_out;
  float* ws = (float*)d_ws;

  float* Wt    = ws;               // 2,048,000
  float* emb   = Wt + 2048000;     // 2,097,152
  float* xpa   = emb + 2097152;    // 6,291,456
  float* xpb   = xpa + 6291456;    // 6,291,456
  float* aoutB = xpb + 6291456;    // 2,097,152
  float* boutB = aoutB + 2097152;  // 2,097,152
  float* betaB = boutB + 2097152;  // 2,097,152
  float* alpha = betaB + 2097152;  // 8,192
  float* comb  = alpha + 8192;     // 36,864
  float* h1    = comb + 36864;     // 32,768
  float* h2    = h1 + 32768;       // 32,768
  float* W1p   = h2 + 32768;       // 73,728
  float* W1pd  = W1p + 73728;      // 73,728
  short* wbf   = (short*)(W1pd + 73728);  // 2*8*3*16*64*8 = 393,216 shorts

  transpose_w<<<dim3(250, 8), dim3(32, 8), 0, stream>>>(embW, Wt);
  pad_w1<<<dim3(576), dim3(256), 0, stream>>>(clsW1, dlW1, W1p, W1pd);
  pack_whh<<<dim3(96), dim3(512), 0, stream>>>(aWhh, bWhh, wbf);
  embed_sparse<<<dim3(8192), dim3(256), 0, stream>>>(x, Wt, embB, emb);
  gemm_dual<<<dim3(12, 128), dim3(256), 0, stream>>>(emb, aWih, bWih, abih, bbih, xpa, xpb, 256);
  gru_scan<<<dim3(64), dim3(1024), 0, stream>>>(xpa, xpb, wbf, abhh, bbhh, aoutB, boutB);
  alpha_softmax<<<dim3(128), dim3(256), 0, stream>>>(aoutB, attnAW, attnAb, alpha);
  gemm_bt<<<dim3(4, 128), dim3(256), 0, stream>>>(boutB, attnBW, attnBb, betaB, 8192, 256, 256, 256, 2);
  context_combined<<<dim3(128), dim3(256), 0, stream>>>(alpha, emb, betaB, demo, comb);
  gemm_bt<<<dim3(4, 2), dim3(256), 0, stream>>>(comb, W1p, clsb1, h1, 128, 256, 288, 256, 1);
  gemm_bt<<<dim3(4, 2), dim3(256), 0, stream>>>(comb, W1pd, dlb1, h2, 128, 256, 288, 256, 1);
  gemm_bt<<<dim3(125, 2), dim3(256), 0, stream>>>(h1, clsW2, clsb2, out, 128, 8000, 256, 8001, 0);
  dl_head<<<dim3(128), dim3(64), 0, stream>>>(h2, dlW2, dlb2, out);
}

// Round 12
// 278.217 us; speedup vs baseline: 3.9070x; 1.3276x over previous
//
#include <hip/hip_runtime.h>

// RETAIN forward. B=128 T=64 C=8000 H=256 D=16 G=768. All fp32 in/out;
// bf16 MFMA for matmuls, fp32 everywhere else.

typedef __attribute__((ext_vector_type(4))) float f32x4;
typedef __attribute__((ext_vector_type(8))) short short8;

__device__ inline short f2bf(float f) {
  unsigned u = __float_as_uint(f);
  u += 0x7fffu + ((u >> 16) & 1u);
  return (short)(u >> 16);
}
__device__ inline float sigf(float x) { return 1.f / (1.f + __expf(-x)); }
__device__ inline float tanh_fast(float x) {
  x = fminf(fmaxf(x, -15.f), 15.f);
  float e = __expf(2.f * x);
  return (e - 1.f) / (e + 1.f);
}

// ---------------- transpose embed_W [256,8000] -> Wt [8000,256] ----------------
__global__ void transpose_w(const float* __restrict__ in, float* __restrict__ outT) {
  __shared__ float tile[32][33];
  const int tx = threadIdx.x, ty = threadIdx.y;
  const int c0 = blockIdx.x * 32, h0 = blockIdx.y * 32;
#pragma unroll
  for (int k = 0; k < 4; ++k)
    tile[ty * 4 + k][tx] = in[(long)(h0 + ty * 4 + k) * 8000 + c0 + tx];
  __syncthreads();
#pragma unroll
  for (int k = 0; k < 4; ++k)
    outT[(long)(c0 + ty * 4 + k) * 256 + h0 + tx] = tile[tx][ty * 4 + k];
}

// ---------------- pad cls_W1/dl_W1 [256,272] -> [256,288] (zeros) ----------------
__global__ __launch_bounds__(256) void pad_w1(const float* __restrict__ w1,
                                              const float* __restrict__ w1d,
                                              float* __restrict__ o1,
                                              float* __restrict__ o2) {
  int idx = blockIdx.x * 256 + threadIdx.x;
  if (idx >= 2 * 256 * 288) return;
  int half = idx / (256 * 288);
  int r = idx % (256 * 288);
  int n = r / 288, k = r % 288;
  float v = (k < 272) ? (half ? w1d[n * 272 + k] : w1[n * 272 + k]) : 0.f;
  if (half) o2[r] = v; else o1[r] = v;
}

// ---------------- pack W_hh into bf16 MFMA fragments ----------------
// frag F = (((gru*8 + kt)*3 + e)*16 + w)*64 + lane ; 8 shorts each.
// lane holds W[g = e*256 + w*16 + (lane&15)][kt*32 + (lane>>4)*8 + j]
__global__ __launch_bounds__(512) void pack_whh(const float* __restrict__ aWhh,
                                                const float* __restrict__ bWhh,
                                                short* __restrict__ wbf) {
  const int F = blockIdx.x * 512 + threadIdx.x;  // 0..49151
  int f = F;
  const int lane = f & 63; f >>= 6;
  const int w = f & 15; f >>= 4;
  const int e = f % 3; f /= 3;
  const int kt = f & 7; f >>= 3;
  const int gru = f;
  const float* W = gru ? bWhh : aWhh;
  const int g = e * 256 + w * 16 + (lane & 15);
  const int k = kt * 32 + (lane >> 4) * 8;
  const float* p = W + (long)g * 256 + k;
  short8 v;
#pragma unroll
  for (int j = 0; j < 8; ++j) v[j] = f2bf(p[j]);
  *(short8*)(wbf + (long)F * 8) = v;
}

// ---------------- sparse embed: emb[bt,h] = b[h] + sum_c x!=0 * Wt[c,h] ----------------
__global__ __launch_bounds__(256) void embed_sparse(const float* __restrict__ x,
                                                    const float* __restrict__ Wt,
                                                    const float* __restrict__ eb,
                                                    float* __restrict__ emb) {
  __shared__ int sidx[512];
  __shared__ float sval[512];
  __shared__ int scnt;
  const int bt = blockIdx.x;  // 0..8191
  const int tid = threadIdx.x;
  if (tid == 0) scnt = 0;
  __syncthreads();
  const float* xr = x + (long)bt * 8000;
  for (int i = tid; i < 2000; i += 256) {
    float4 v = ((const float4*)xr)[i];
    if (v.x != 0.f) { int p = atomicAdd(&scnt, 1); if (p < 512) { sidx[p] = i * 4 + 0; sval[p] = v.x; } }
    if (v.y != 0.f) { int p = atomicAdd(&scnt, 1); if (p < 512) { sidx[p] = i * 4 + 1; sval[p] = v.y; } }
    if (v.z != 0.f) { int p = atomicAdd(&scnt, 1); if (p < 512) { sidx[p] = i * 4 + 2; sval[p] = v.z; } }
    if (v.w != 0.f) { int p = atomicAdd(&scnt, 1); if (p < 512) { sidx[p] = i * 4 + 3; sval[p] = v.w; } }
  }
  __syncthreads();
  const int n = min(scnt, 512);
  float acc = eb[tid];
  for (int i = 0; i < n; ++i) acc += sval[i] * Wt[(long)sidx[i] * 256 + tid];
  emb[(long)bt * 256 + tid] = acc;
}

// ---------------- generic GEMM: C[M,N] = act(A[M,K] @ B[N,K]^T + bias) ----------------
__global__ __launch_bounds__(256) void gemm_bt(const float* __restrict__ A,
                                               const float* __restrict__ B,
                                               const float* __restrict__ bias,
                                               float* __restrict__ C,
                                               int M, int N, int K, int ldc, int act) {
  __shared__ short As[64][40];
  __shared__ short Bs[64][40];
  const int tid = threadIdx.x;
  const int lane = tid & 63, wave = tid >> 6;
  const int wm = wave >> 1, wn = wave & 1;
  const int l15 = lane & 15, lhi = lane >> 4;
  const int m0 = blockIdx.y * 64, n0 = blockIdx.x * 64;
  const int srow = tid >> 2, scol = (tid & 3) * 8;
  f32x4 acc[2][2];
#pragma unroll
  for (int i = 0; i < 2; ++i)
#pragma unroll
    for (int j = 0; j < 2; ++j) acc[i][j] = (f32x4){0.f, 0.f, 0.f, 0.f};

  for (int k0 = 0; k0 < K; k0 += 32) {
    __syncthreads();
    {
      const float* p = A + (long)(m0 + srow) * K + k0 + scol;
      float4 f0 = *(const float4*)p;
      float4 f1 = *(const float4*)(p + 4);
      short8 v;
      v[0] = f2bf(f0.x); v[1] = f2bf(f0.y); v[2] = f2bf(f0.z); v[3] = f2bf(f0.w);
      v[4] = f2bf(f1.x); v[5] = f2bf(f1.y); v[6] = f2bf(f1.z); v[7] = f2bf(f1.w);
      *(short8*)&As[srow][scol] = v;
      const float* q = B + (long)(n0 + srow) * K + k0 + scol;
      float4 g0 = *(const float4*)q;
      float4 g1 = *(const float4*)(q + 4);
      short8 u;
      u[0] = f2bf(g0.x); u[1] = f2bf(g0.y); u[2] = f2bf(g0.z); u[3] = f2bf(g0.w);
      u[4] = f2bf(g1.x); u[5] = f2bf(g1.y); u[6] = f2bf(g1.z); u[7] = f2bf(g1.w);
      *(short8*)&Bs[srow][scol] = u;
    }
    __syncthreads();
    short8 af0 = *(const short8*)&As[wm * 32 + l15][lhi * 8];
    short8 af1 = *(const short8*)&As[wm * 32 + 16 + l15][lhi * 8];
    short8 bf0 = *(const short8*)&Bs[wn * 32 + l15][lhi * 8];
    short8 bf1 = *(const short8*)&Bs[wn * 32 + 16 + l15][lhi * 8];
    acc[0][0] = __builtin_amdgcn_mfma_f32_16x16x32_bf16(af0, bf0, acc[0][0], 0, 0, 0);
    acc[0][1] = __builtin_amdgcn_mfma_f32_16x16x32_bf16(af0, bf1, acc[0][1], 0, 0, 0);
    acc[1][0] = __builtin_amdgcn_mfma_f32_16x16x32_bf16(af1, bf0, acc[1][0], 0, 0, 0);
    acc[1][1] = __builtin_amdgcn_mfma_f32_16x16x32_bf16(af1, bf1, acc[1][1], 0, 0, 0);
  }
#pragma unroll
  for (int j = 0; j < 2; ++j) {
    const int col = n0 + wn * 32 + j * 16 + l15;
    const float bv = bias[col];
#pragma unroll
    for (int i = 0; i < 2; ++i) {
#pragma unroll
      for (int r = 0; r < 4; ++r) {
        const int row = m0 + wm * 32 + i * 16 + lhi * 4 + r;
        float v = acc[i][j][r] + bv;
        if (act == 1) v = fmaxf(v, 0.f);
        else if (act == 2) v = tanh_fast(v);
        C[(long)row * ldc + col] = v;
      }
    }
  }
}

// ---------------- dual-B GEMM: xpa/xpb from emb in one pass (A read once) ----------------
__global__ __launch_bounds__(256) void gemm_dual(const float* __restrict__ A,
                                                 const float* __restrict__ B1,
                                                 const float* __restrict__ B2,
                                                 const float* __restrict__ bias1,
                                                 const float* __restrict__ bias2,
                                                 float* __restrict__ C1,
                                                 float* __restrict__ C2,
                                                 int K) {
  __shared__ short As[64][40];
  __shared__ short Bs1[64][40];
  __shared__ short Bs2[64][40];
  const int tid = threadIdx.x;
  const int lane = tid & 63, wave = tid >> 6;
  const int wm = wave >> 1, wn = wave & 1;
  const int l15 = lane & 15, lhi = lane >> 4;
  const int m0 = blockIdx.y * 64, n0 = blockIdx.x * 64;
  const int srow = tid >> 2, scol = (tid & 3) * 8;
  f32x4 acc1[2][2], acc2[2][2];
#pragma unroll
  for (int i = 0; i < 2; ++i)
#pragma unroll
    for (int j = 0; j < 2; ++j) {
      acc1[i][j] = (f32x4){0.f, 0.f, 0.f, 0.f};
      acc2[i][j] = (f32x4){0.f, 0.f, 0.f, 0.f};
    }

  for (int k0 = 0; k0 < K; k0 += 32) {
    __syncthreads();
    {
      const float* p = A + (long)(m0 + srow) * K + k0 + scol;
      float4 f0 = *(const float4*)p;
      float4 f1 = *(const float4*)(p + 4);
      short8 v;
      v[0] = f2bf(f0.x); v[1] = f2bf(f0.y); v[2] = f2bf(f0.z); v[3] = f2bf(f0.w);
      v[4] = f2bf(f1.x); v[5] = f2bf(f1.y); v[6] = f2bf(f1.z); v[7] = f2bf(f1.w);
      *(short8*)&As[srow][scol] = v;
      const float* q1 = B1 + (long)(n0 + srow) * K + k0 + scol;
      float4 g0 = *(const float4*)q1;
      float4 g1 = *(const float4*)(q1 + 4);
      short8 u;
      u[0] = f2bf(g0.x); u[1] = f2bf(g0.y); u[2] = f2bf(g0.z); u[3] = f2bf(g0.w);
      u[4] = f2bf(g1.x); u[5] = f2bf(g1.y); u[6] = f2bf(g1.z); u[7] = f2bf(g1.w);
      *(short8*)&Bs1[srow][scol] = u;
      const float* q2 = B2 + (long)(n0 + srow) * K + k0 + scol;
      float4 h0 = *(const float4*)q2;
      float4 h1 = *(const float4*)(q2 + 4);
      short8 t;
      t[0] = f2bf(h0.x); t[1] = f2bf(h0.y); t[2] = f2bf(h0.z); t[3] = f2bf(h0.w);
      t[4] = f2bf(h1.x); t[5] = f2bf(h1.y); t[6] = f2bf(h1.z); t[7] = f2bf(h1.w);
      *(short8*)&Bs2[srow][scol] = t;
    }
    __syncthreads();
    short8 af0 = *(const short8*)&As[wm * 32 + l15][lhi * 8];
    short8 af1 = *(const short8*)&As[wm * 32 + 16 + l15][lhi * 8];
    short8 b10 = *(const short8*)&Bs1[wn * 32 + l15][lhi * 8];
    short8 b11 = *(const short8*)&Bs1[wn * 32 + 16 + l15][lhi * 8];
    short8 b20 = *(const short8*)&Bs2[wn * 32 + l15][lhi * 8];
    short8 b21 = *(const short8*)&Bs2[wn * 32 + 16 + l15][lhi * 8];
    acc1[0][0] = __builtin_amdgcn_mfma_f32_16x16x32_bf16(af0, b10, acc1[0][0], 0, 0, 0);
    acc1[0][1] = __builtin_amdgcn_mfma_f32_16x16x32_bf16(af0, b11, acc1[0][1], 0, 0, 0);
    acc1[1][0] = __builtin_amdgcn_mfma_f32_16x16x32_bf16(af1, b10, acc1[1][0], 0, 0, 0);
    acc1[1][1] = __builtin_amdgcn_mfma_f32_16x16x32_bf16(af1, b11, acc1[1][1], 0, 0, 0);
    acc2[0][0] = __builtin_amdgcn_mfma_f32_16x16x32_bf16(af0, b20, acc2[0][0], 0, 0, 0);
    acc2[0][1] = __builtin_amdgcn_mfma_f32_16x16x32_bf16(af0, b21, acc2[0][1], 0, 0, 0);
    acc2[1][0] = __builtin_amdgcn_mfma_f32_16x16x32_bf16(af1, b20, acc2[1][0], 0, 0, 0);
    acc2[1][1] = __builtin_amdgcn_mfma_f32_16x16x32_bf16(af1, b21, acc2[1][1], 0, 0, 0);
  }
#pragma unroll
  for (int j = 0; j < 2; ++j) {
    const int col = n0 + wn * 32 + j * 16 + l15;
    const float bv1 = bias1[col];
    const float bv2 = bias2[col];
#pragma unroll
    for (int i = 0; i < 2; ++i) {
#pragma unroll
      for (int r = 0; r < 4; ++r) {
        const int row = m0 + wm * 32 + i * 16 + lhi * 4 + r;
        C1[(long)row * 768 + col] = acc1[i][j][r] + bv1;
        C2[(long)row * 768 + col] = acc2[i][j][r] + bv2;
      }
    }
  }
}

// ---------------- GRU scan v12 ----------------
// v11 structure (batch b -> MFMA row 4b, all-64-lane elementwise, double-buffered
// hl+xpl, ONE __syncthreads/step) but xp staging reverted to the PROVEN R10
// pattern: 12 waves x width-16 global_load_lds (v11's width-12 staging is the
// prime correctness suspect -- only 4B/16B widths are HW-verified).
__global__ __launch_bounds__(1024, 4)
void gru_scan(const float* __restrict__ xpa,
              const float* __restrict__ xpb,
              const short* __restrict__ wbf,
              const float* __restrict__ abhh,
              const float* __restrict__ bbhh,
              float* __restrict__ aout,
              float* __restrict__ bout) {
  const int tid = threadIdx.x;
  const int lane = tid & 63, w = tid >> 6;   // wave 0..15
  const int l15 = lane & 15, lhi = lane >> 4;
  const int gru = blockIdx.x >> 5, chunk = blockIdx.x & 31;
  const int b0 = chunk * 4;
  const float* xp  = gru ? xpb : xpa;
  const float* bhh = gru ? bbhh : abhh;
  float* outp = gru ? bout : aout;

  __shared__ short hl[2][16][264];         // 16.9 KB double-buffered h (rows 4b real)
  __shared__ float xpl[2][4][776];         // 24.8 KB double-buffered xp slice
  __shared__ short wlds[2][16][3][64][8];  // 96 KB: kt 4,5 fragments

  // fragment pointer: F = (((gru*8+kt)*3+e)*16 + w)*64 + lane
  auto FR = [&](int kt, int e) -> const short8* {
    return (const short8*)(wbf + ((((long)gru * 8 + kt) * 3 + e) * 16 + w) * 512 + (long)lane * 8);
  };

  // kt 0..3 -> registers
  short8 wf[3][4];
#pragma unroll
  for (int e = 0; e < 3; ++e)
#pragma unroll
    for (int kt = 0; kt < 4; ++kt) wf[e][kt] = *FR(kt, e);
  // kt 4..5 -> LDS
#pragma unroll
  for (int e = 0; e < 3; ++e)
#pragma unroll
    for (int kt = 4; kt < 6; ++kt) *(short8*)&wlds[kt - 4][w][e][lane][0] = *FR(kt, e);

  float bh[3];
#pragma unroll
  for (int e = 0; e < 3; ++e) bh[e] = bhh[e * 256 + w * 16 + l15];

  for (int i = tid; i < 2 * 16 * 264; i += 1024) (&hl[0][0][0])[i] = 0;

  // stage xp[tt] -> xpl[par]: waves 0..11, row=w/3, seg=w%3 (1KB contiguous,
  // width-16 global_load_lds; dest = uniform base + lane*16B) -- R10-proven.
  auto STAGE = [&](int par, int tt) {
    const int row = w / 3, seg = w % 3;
    const float* gp = xp + ((long)(b0 + row) * 64 + tt) * 768 + seg * 256 + lane * 4;
    __builtin_amdgcn_global_load_lds((const __attribute__((address_space(1))) unsigned int*)gp,
                                     (__attribute__((address_space(3))) unsigned int*)&xpl[par][row][seg * 256],
                                     16, 0, 0);
  };
  if (w < 12) STAGE(0, 0);
  __syncthreads();  // weights/hl visible, xpl[0] landed

  float hreg = 0.f;  // h state: batch lhi, col w*16+l15
  const int col = w * 16 + l15;

  for (int t = 0; t < 64; ++t) {
    const int cur = t & 1;
    // streamed weights kt 6,7 (L2-resident fragment table)
    short8 s60 = *FR(6, 0), s61 = *FR(6, 1), s62 = *FR(6, 2);
    short8 s70 = *FR(7, 0), s71 = *FR(7, 1), s72 = *FR(7, 2);
    if (t + 1 < 64 && w < 12) STAGE(cur ^ 1, t + 1);  // in flight until end-of-step sync

    f32x4 acc[3];
#pragma unroll
    for (int e = 0; e < 3; ++e) acc[e] = (f32x4){0.f, 0.f, 0.f, 0.f};
#pragma unroll
    for (int kt = 0; kt < 4; ++kt) {
      short8 a = *(const short8*)&hl[cur][l15][kt * 32 + lhi * 8];
      acc[0] = __builtin_amdgcn_mfma_f32_16x16x32_bf16(a, wf[0][kt], acc[0], 0, 0, 0);
      acc[1] = __builtin_amdgcn_mfma_f32_16x16x32_bf16(a, wf[1][kt], acc[1], 0, 0, 0);
      acc[2] = __builtin_amdgcn_mfma_f32_16x16x32_bf16(a, wf[2][kt], acc[2], 0, 0, 0);
    }
#pragma unroll
    for (int kt = 4; kt < 6; ++kt) {
      short8 a = *(const short8*)&hl[cur][l15][kt * 32 + lhi * 8];
#pragma unroll
      for (int e = 0; e < 3; ++e) {
        short8 wl = *(const short8*)&wlds[kt - 4][w][e][lane][0];
        acc[e] = __builtin_amdgcn_mfma_f32_16x16x32_bf16(a, wl, acc[e], 0, 0, 0);
      }
    }
    {
      short8 a = *(const short8*)&hl[cur][l15][6 * 32 + lhi * 8];
      acc[0] = __builtin_amdgcn_mfma_f32_16x16x32_bf16(a, s60, acc[0], 0, 0, 0);
      acc[1] = __builtin_amdgcn_mfma_f32_16x16x32_bf16(a, s61, acc[1], 0, 0, 0);
      acc[2] = __builtin_amdgcn_mfma_f32_16x16x32_bf16(a, s62, acc[2], 0, 0, 0);
    }
    {
      short8 a = *(const short8*)&hl[cur][l15][7 * 32 + lhi * 8];
      acc[0] = __builtin_amdgcn_mfma_f32_16x16x32_bf16(a, s70, acc[0], 0, 0, 0);
      acc[1] = __builtin_amdgcn_mfma_f32_16x16x32_bf16(a, s71, acc[1], 0, 0, 0);
      acc[2] = __builtin_amdgcn_mfma_f32_16x16x32_bf16(a, s72, acc[2], 0, 0, 0);
    }

    // elementwise: all 64 lanes; lane (lhi,l15) = (batch lhi, col); acc[e][0]
    // is C row 4*lhi = batch lhi (batches live at MFMA rows 0,4,8,12).
    {
      const float xr = xpl[cur][lhi][col];
      const float xz = xpl[cur][lhi][256 + col];
      const float xn = xpl[cur][lhi][512 + col];
      const float r = sigf(xr + acc[0][0] + bh[0]);
      const float z = sigf(xz + acc[1][0] + bh[1]);
      const float n = tanh_fast(xn + r * (acc[2][0] + bh[2]));
      const float hn = (1.f - z) * n + z * hreg;
      hreg = hn;
      hl[cur ^ 1][lhi << 2][col] = f2bf(hn);
      outp[((long)(b0 + lhi) * 64 + t) * 256 + col] = hn;
    }
    // single sync: drains vmcnt(0) (t+1 stage landed after ~a full step in
    // flight) + lgkmcnt(0) (hl writes visible), barriers all 16 waves.
    __syncthreads();
  }
}

// ---------------- e_alpha + softmax over T ----------------
__global__ __launch_bounds__(256) void alpha_softmax(const float* __restrict__ aout,
                                                     const float* __restrict__ aW,
                                                     const float* __restrict__ ab,
                                                     float* __restrict__ alpha) {
  __shared__ float part[64][4];
  const int b = blockIdx.x, tid = threadIdx.x;
  const int t = tid >> 2, q = tid & 3;
  const float* p = aout + (long)(b * 64 + t) * 256 + q * 64;
  const float* wv = aW + q * 64;
  float s = 0.f;
  for (int i = 0; i < 64; ++i) s += p[i] * wv[i];
  part[t][q] = s;
  __syncthreads();
  if (tid < 64) {
    float e = part[tid][0] + part[tid][1] + part[tid][2] + part[tid][3] + ab[0];
    float m = e;
    for (int k = 32; k; k >>= 1) m = fmaxf(m, __shfl_xor(m, k));
    float ex = __expf(e - m);
    float sum = ex;
    for (int k = 32; k; k >>= 1) sum += __shfl_xor(sum, k);
    alpha[b * 64 + tid] = ex / sum;
  }
}

// ---------------- context + combined[B,288] (context|demo|zero-pad) ----------------
__global__ __launch_bounds__(256) void context_combined(const float* __restrict__ alpha,
                                                        const float* __restrict__ emb,
                                                        const float* __restrict__ beta,
                                                        const float* __restrict__ demo,
                                                        float* __restrict__ comb) {
  const int b = blockIdx.x, h = threadIdx.x;
  float acc = 0.f;
  for (int t = 0; t < 64; ++t) {
    const float a = alpha[b * 64 + t];
    const long ix = (long)(b * 64 + t) * 256 + h;
    acc += a * emb[ix] * beta[ix];
  }
  comb[b * 288 + h] = acc;
  if (h < 16) comb[b * 288 + 256 + h] = demo[b * 16 + h];
  else if (h < 32) comb[b * 288 + 256 + h] = 0.f;
}

// ---------------- death/LOS head final dot ----------------
__global__ __launch_bounds__(64) void dl_head(const float* __restrict__ h2,
                                              const float* __restrict__ w,
                                              const float* __restrict__ bias,
                                              float* __restrict__ out) {
  const int b = blockIdx.x, lane = threadIdx.x;
  float s = 0.f;
#pragma unroll
  for (int i = 0; i < 4; ++i) s += h2[b * 256 + lane * 4 + i] * w[lane * 4 + i];
  for (int k = 32; k; k >>= 1) s += __shfl_xor(s, k);
  if (lane == 0) out[(long)b * 8001 + 8000] = s + bias[0];
}

extern "C" void kernel_launch(void* const* d_in, const int* in_sizes, int n_in,
                              void* d_out, int out_size, void* d_ws, size_t ws_size,
                              hipStream_t stream) {
  (void)in_sizes; (void)n_in; (void)out_size; (void)ws_size;
  const float* x      = (const float*)d_in[0];
  const float* demo   = (const float*)d_in[1];
  const float* embW   = (const float*)d_in[2];
  const float* embB   = (const float*)d_in[3];
  const float* aWih   = (const float*)d_in[4];
  const float* aWhh   = (const float*)d_in[5];
  const float* abih   = (const float*)d_in[6];
  const float* abhh   = (const float*)d_in[7];
  const float* bWih   = (const float*)d_in[8];
  const float* bWhh   = (const float*)d_in[9];
  const float* bbih   = (const float*)d_in[10];
  const float* bbhh   = (const float*)d_in[11];
  const float* attnAW = (const float*)d_in[12];
  const float* attnAb = (const float*)d_in[13];
  const float* attnBW = (const float*)d_in[14];
  const float* attnBb = (const float*)d_in[15];
  const float* clsW1  = (const float*)d_in[16];
  const float* clsb1  = (const float*)d_in[17];
  const float* clsW2  = (const float*)d_in[18];
  const float* clsb2  = (const float*)d_in[19];
  const float* dlW1   = (const float*)d_in[20];
  const float* dlb1   = (const float*)d_in[21];
  const float* dlW2   = (const float*)d_in[22];
  const float* dlb2   = (const float*)d_in[23];
  float* out = (float*)d_out;
  float* ws = (float*)d_ws;

  float* Wt    = ws;               // 2,048,000
  float* emb   = Wt + 2048000;     // 2,097,152
  float* xpa   = emb + 2097152;    // 6,291,456
  float* xpb   = xpa + 6291456;    // 6,291,456
  float* aoutB = xpb + 6291456;    // 2,097,152
  float* boutB = aoutB + 2097152;  // 2,097,152
  float* betaB = boutB + 2097152;  // 2,097,152
  float* alpha = betaB + 2097152;  // 8,192
  float* comb  = alpha + 8192;     // 36,864
  float* h1    = comb + 36864;     // 32,768
  float* h2    = h1 + 32768;       // 32,768
  float* W1p   = h2 + 32768;       // 73,728
  float* W1pd  = W1p + 73728;      // 73,728
  short* wbf   = (short*)(W1pd + 73728);  // 2*8*3*16*64*8 = 393,216 shorts

  transpose_w<<<dim3(250, 8), dim3(32, 8), 0, stream>>>(embW, Wt);
  pad_w1<<<dim3(576), dim3(256), 0, stream>>>(clsW1, dlW1, W1p, W1pd);
  pack_whh<<<dim3(96), dim3(512), 0, stream>>>(aWhh, bWhh, wbf);
  embed_sparse<<<dim3(8192), dim3(256), 0, stream>>>(x, Wt, embB, emb);
  gemm_dual<<<dim3(12, 128), dim3(256), 0, stream>>>(emb, aWih, bWih, abih, bbih, xpa, xpb, 256);
  gru_scan<<<dim3(64), dim3(1024), 0, stream>>>(xpa, xpb, wbf, abhh, bbhh, aoutB, boutB);
  alpha_softmax<<<dim3(128), dim3(256), 0, stream>>>(aoutB, attnAW, attnAb, alpha);
  gemm_bt<<<dim3(4, 128), dim3(256), 0, stream>>>(boutB, attnBW, attnBb, betaB, 8192, 256, 256, 256, 2);
  context_combined<<<dim3(128), dim3(256), 0, stream>>>(alpha, emb, betaB, demo, comb);
  gemm_bt<<<dim3(4, 2), dim3(256), 0, stream>>>(comb, W1p, clsb1, h1, 128, 256, 288, 256, 1);
  gemm_bt<<<dim3(4, 2), dim3(256), 0, stream>>>(comb, W1pd, dlb1, h2, 128, 256, 288, 256, 1);
  gemm_bt<<<dim3(125, 2), dim3(256), 0, stream>>>(h1, clsW2, clsb2, out, 128, 8000, 256, 8001, 0);
  dl_head<<<dim3(128), dim3(64), 0, stream>>>(h2, dlW2, dlb2, out);
}